// Round 5
// baseline (144.627 us; speedup 1.0000x reference)
//
#include <hip/hip_runtime.h>
#include <math.h>

typedef __bf16 bf16;
typedef __bf16 bf16x8 __attribute__((ext_vector_type(8)));
typedef __bf16 bf16x4 __attribute__((ext_vector_type(4)));
typedef float  f32x4  __attribute__((ext_vector_type(4)));

constexpr int BATCH = 4096;
constexpr int HID   = 512;
constexpr int NSTEP = 16;
constexpr int SLICE = BATCH * HID;   // elements per [B,H] plane

__device__ __forceinline__ float sigmoidf_(float x) {
    return 1.0f / (1.0f + __expf(-x));
}
__device__ __forceinline__ float tanh_fast(float x) {
    x = fminf(fmaxf(x, -15.0f), 15.0f);
    float e = __expf(2.0f * x);
    return (e - 1.0f) / (e + 1.0f);
}

__device__ __forceinline__ void gload_lds16(const void* g, void* l) {
    __builtin_amdgcn_global_load_lds((const __attribute__((address_space(1))) void*)g,
                                     (__attribute__((address_space(3))) void*)l,
                                     16, 0, 0);
}

// ---------------------------------------------------------------------------
// Fused prep: blocks [0,6144) convert sample/hidden/mem_para f32->bf16;
// blocks [6144,8704) transpose-convert the five weight matrices to B^T bf16.
__global__ __launch_bounds__(256)
void prep_all(const float* __restrict__ sample,
              const float* __restrict__ hidden,
              const float* __restrict__ mem_para,
              const float* __restrict__ Wu, const float* __restrict__ Wr,
              const float* __restrict__ Wm, const float* __restrict__ Wh,
              const float* __restrict__ Wo,
              bf16* __restrict__ Sb, bf16* __restrict__ Hb, bf16* __restrict__ Mb,
              bf16* __restrict__ Wall_t, bf16* __restrict__ Wh_t,
              bf16* __restrict__ Wo_t) {
    __shared__ float tile[32][33];
    const int bid = blockIdx.x;
    if (bid < 6144) {
        const int seg = bid >> 11;              // 0,1,2
        const int i = (bid & 2047) * 256 + threadIdx.x; // float4 index < SLICE/4
        const float* in = (seg == 0) ? sample : (seg == 1) ? hidden : mem_para;
        bf16* out = (seg == 0) ? Sb : (seg == 1) ? Hb : Mb;
        float4 v = ((const float4*)in)[i];
        bf16x4 o = {(bf16)v.x, (bf16)v.y, (bf16)v.z, (bf16)v.w};
        ((bf16x4*)out)[i] = o;
        return;
    }
    const int t = bid - 6144;                   // 0..2559: 32x32 transpose tiles
    const float* in; bf16* out; int stride, row_off, t2;
    if (t < 512)        { in = Wu; out = Wall_t; stride = 1536; row_off = 0;    t2 = t; }
    else if (t < 1024)  { in = Wr; out = Wall_t; stride = 1536; row_off = 512;  t2 = t - 512; }
    else if (t < 1792)  { in = Wm; out = Wall_t; stride = 1536; row_off = 1024; t2 = t - 1024; }
    else if (t < 2304)  { in = Wh; out = Wh_t;   stride = 1024; row_off = 0;    t2 = t - 1792; }
    else                { in = Wo; out = Wo_t;   stride = 512;  row_off = 0;    t2 = t - 2304; }
    const int r0 = (t2 >> 4) * 32, c0 = (t2 & 15) * 32;
    const int tr = threadIdx.x >> 5;   // 0..7
    const int tc = threadIdx.x & 31;   // 0..31
#pragma unroll
    for (int i = 0; i < 4; ++i)
        tile[tr + i * 8][tc] = in[(size_t)(r0 + tr + i * 8) * 512 + c0 + tc];
    __syncthreads();
#pragma unroll
    for (int i = 0; i < 4; ++i) {
        const int c = tr + i * 8;
        out[(size_t)(row_off + c0 + c) * stride + r0 + tc] = (bf16)tile[tc][c];
    }
}

// ---------------------------------------------------------------------------
// Fused U|R|M GEMM, tile BM=128 BN=128 BK=64 (m97 structure), 4 waves 2x2,
// wave tile 64x64 (4x4 16x16x32 frags). Per-block K count: U/R columns
// (bcol<1024) use K=1024 (16 tiles); M columns use K=1536 (24 tiles) --
// Wall_t rows 0..1023 have garbage at k>=1024 that is never read.
// Epilogue: col<512: ug=sigmoid -> bf16 UGb; <1024: rh=sigmoid*hb -> bf16 RHb;
//           >=1024: mg=0.5*sigmoid -> f32 out_mg.
__global__ __launch_bounds__(256)
void gemm_urm(const bf16* __restrict__ Sb,
              const bf16* __restrict__ Hb,
              const bf16* __restrict__ Mb,
              const bf16* __restrict__ Wall_t,
              const float* __restrict__ bu,
              const float* __restrict__ br,
              const float* __restrict__ bm,
              bf16* __restrict__ UGb,
              bf16* __restrict__ RHb,
              float* __restrict__ out_mg) {
    __shared__ bf16 As[128 * 64];   // 16KB
    __shared__ bf16 Bs[128 * 64];   // 16KB

    const int tid  = threadIdx.x;
    const int wid  = tid >> 6;
    const int lane = tid & 63;
    const int wr = wid >> 1, wc = wid & 1;
    const int brow = blockIdx.x * 128;
    const int bcol = blockIdx.y * 128;

    const bf16* segs[3] = {Sb, Hb, Mb};
    const int nkt = (bcol >= 1024) ? 24 : 16;

    const int s_row  = tid >> 3;   // 0..31 (plus c*32)
    const int s_chnk = tid & 7;

    f32x4 acc[4][4] = {};

    for (int t = 0; t < nkt; ++t) {
        const int k0 = t * 64;
        const bf16* Aseg = segs[k0 >> 9];
        const int kloc = k0 & 511;

#pragma unroll
        for (int c = 0; c < 4; ++c) {
            const int row = c * 32 + s_row;
            const int sc  = s_chnk ^ (row & 7);
            gload_lds16(Aseg + (size_t)(brow + row) * 512 + kloc + sc * 8,
                        As + (size_t)(c * 256 + (wid << 6)) * 8);
        }
#pragma unroll
        for (int c = 0; c < 4; ++c) {
            const int row = c * 32 + s_row;
            const int sc  = s_chnk ^ (row & 7);
            gload_lds16(Wall_t + (size_t)(bcol + row) * 1536 + k0 + sc * 8,
                        Bs + (size_t)(c * 256 + (wid << 6)) * 8);
        }
        __syncthreads();

#pragma unroll
        for (int ks = 0; ks < 2; ++ks) {
            const int kb = ks * 64 + ((lane >> 4) << 4);
            bf16x8 bfrag[4];
#pragma unroll
            for (int ni = 0; ni < 4; ++ni) {
                const int n = wc * 64 + ni * 16 + (lane & 15);
                bfrag[ni] = *(const bf16x8*)((const char*)Bs +
                                             n * 128 + (kb ^ ((n & 7) << 4)));
            }
#pragma unroll
            for (int mi = 0; mi < 4; ++mi) {
                const int m = wr * 64 + mi * 16 + (lane & 15);
                const bf16x8 afrag = *(const bf16x8*)((const char*)As +
                                                      m * 128 + (kb ^ ((m & 7) << 4)));
#pragma unroll
                for (int ni = 0; ni < 4; ++ni)
                    acc[mi][ni] = __builtin_amdgcn_mfma_f32_16x16x32_bf16(
                        afrag, bfrag[ni], acc[mi][ni], 0, 0, 0);
            }
        }
        __syncthreads();
    }

    const int lr4 = (lane >> 4) * 4;
    const int lc  = lane & 15;
#pragma unroll
    for (int mi = 0; mi < 4; ++mi) {
#pragma unroll
        for (int ni = 0; ni < 4; ++ni) {
            const int col = bcol + wc * 64 + ni * 16 + lc;
            const f32x4 a = acc[mi][ni];
#pragma unroll
            for (int r = 0; r < 4; ++r) {
                const int row = brow + wr * 64 + mi * 16 + lr4 + r;
                const float x = a[r];
                if (col < 512) {
                    UGb[(size_t)row * 512 + col] = (bf16)sigmoidf_(x + bu[col]);
                } else if (col < 1024) {
                    const int c2 = col - 512;
                    const float v = sigmoidf_(x + br[c2]) *
                                    (float)Hb[(size_t)row * 512 + c2];
                    RHb[(size_t)row * 512 + c2] = (bf16)v;
                } else {
                    const int c3 = col - 1024;
                    out_mg[(size_t)row * 512 + c3] = 0.5f * sigmoidf_(x + bm[c3]);
                }
            }
        }
    }
}

// ---------------------------------------------------------------------------
// Skinny GEMM (N=512): tile BM=128 BN=64 BK=64; 4 waves 2x2, wave 64x32.
// ACT: 2 = tanh -> bf16 outA;  3 = identity(+bias) -> f32 outA
template <int ACT, int KTILES>
__global__ __launch_bounds__(256)
void gemm_mfma(const bf16* __restrict__ segA0,
               const bf16* __restrict__ segA1,
               const bf16* __restrict__ Wt, int ldK,
               const float* __restrict__ b0,
               void* __restrict__ outA) {
    __shared__ bf16 As[128 * 64];   // 16KB
    __shared__ bf16 Bs[64 * 64];    // 8KB

    const int tid  = threadIdx.x;
    const int wid  = tid >> 6;
    const int lane = tid & 63;
    const int wr = wid >> 1, wc = wid & 1;
    const int brow = blockIdx.x * 128;
    const int bcol = blockIdx.y * 64;

    const bf16* segs[2] = {segA0, segA1};

    const int s_row  = tid >> 3;
    const int s_chnk = tid & 7;

    f32x4 acc[4][2] = {};

    for (int t = 0; t < KTILES; ++t) {
        const int k0 = t * 64;
        const bf16* Aseg = segs[k0 >> 9];
        const int kloc = k0 & 511;

#pragma unroll
        for (int c = 0; c < 4; ++c) {
            const int row = c * 32 + s_row;
            const int sc  = s_chnk ^ (row & 7);
            gload_lds16(Aseg + (size_t)(brow + row) * 512 + kloc + sc * 8,
                        As + (size_t)(c * 256 + (wid << 6)) * 8);
        }
#pragma unroll
        for (int c = 0; c < 2; ++c) {
            const int row = c * 32 + s_row;
            const int sc  = s_chnk ^ (row & 7);
            gload_lds16(Wt + (size_t)(bcol + row) * ldK + k0 + sc * 8,
                        Bs + (size_t)(c * 256 + (wid << 6)) * 8);
        }
        __syncthreads();

#pragma unroll
        for (int ks = 0; ks < 2; ++ks) {
            const int kb = ks * 64 + ((lane >> 4) << 4);
            bf16x8 bfrag[2];
#pragma unroll
            for (int ni = 0; ni < 2; ++ni) {
                const int n = wc * 32 + ni * 16 + (lane & 15);
                bfrag[ni] = *(const bf16x8*)((const char*)Bs +
                                             n * 128 + (kb ^ ((n & 7) << 4)));
            }
#pragma unroll
            for (int mi = 0; mi < 4; ++mi) {
                const int m = wr * 64 + mi * 16 + (lane & 15);
                const bf16x8 afrag = *(const bf16x8*)((const char*)As +
                                                      m * 128 + (kb ^ ((m & 7) << 4)));
#pragma unroll
                for (int ni = 0; ni < 2; ++ni)
                    acc[mi][ni] = __builtin_amdgcn_mfma_f32_16x16x32_bf16(
                        afrag, bfrag[ni], acc[mi][ni], 0, 0, 0);
            }
        }
        __syncthreads();
    }

    const int lr4 = (lane >> 4) * 4;
    const int lc  = lane & 15;
#pragma unroll
    for (int mi = 0; mi < 4; ++mi) {
#pragma unroll
        for (int ni = 0; ni < 2; ++ni) {
            const int col = bcol + wc * 32 + ni * 16 + lc;
            const f32x4 a = acc[mi][ni];
#pragma unroll
            for (int r = 0; r < 4; ++r) {
                const int row = brow + wr * 64 + mi * 16 + lr4 + r;
                const float x = a[r];
                if constexpr (ACT == 2) {
                    ((bf16*)outA)[(size_t)row * 512 + col] = (bf16)tanh_fast(x + b0[col]);
                } else {
                    ((float*)outA)[(size_t)row * 512 + col] = x + b0[col];
                }
            }
        }
    }
}

// ---------------------------------------------------------------------------
// Fused memory filter + shifted copy + hidden_now (f32 out + bf16 copy)
__global__ __launch_bounds__(256)
void filter_combine(const float* __restrict__ hiddens,
                    const bf16* __restrict__ ugb,
                    const bf16* __restrict__ htb,
                    const float* __restrict__ mg,
                    float* __restrict__ out_upd,
                    bf16* __restrict__ hnb) {
    const int idx = blockIdx.x * blockDim.x + threadIdx.x;   // float4 index
    const int S4 = SLICE / 4;
    const float4* h4 = (const float4*)hiddens;
    float4* o4 = (float4*)out_upd;

    const float4 d = ((const float4*)mg)[idx];
    float cx = 1.f, cy = 1.f, cz = 1.f, cw = 1.f;
    float ax = 0.f, ay = 0.f, az = 0.f, aw = 0.f;

#pragma unroll
    for (int i = 0; i < NSTEP; ++i) {
        const int j = NSTEP - 1 - i;
        const float4 v = h4[j * S4 + idx];
        const float fi = (float)i;
        const float inv = 1.0f / (float)(i + 1);
        cx *= (fi - d.x) * inv;
        cy *= (fi - d.y) * inv;
        cz *= (fi - d.z) * inv;
        cw *= (fi - d.w) * inv;
        ax = fmaf(v.x, cx, ax);
        ay = fmaf(v.y, cy, ay);
        az = fmaf(v.z, cz, az);
        aw = fmaf(v.w, cw, aw);
        if (j >= 1) o4[(j - 1) * S4 + idx] = v;
    }

    const bf16x4 u4 = ((const bf16x4*)ugb)[idx];
    const bf16x4 t4 = ((const bf16x4*)htb)[idx];
    float4 hn;
    hn.x = fmaf((float)u4[0], (float)t4[0], -ax);
    hn.y = fmaf((float)u4[1], (float)t4[1], -ay);
    hn.z = fmaf((float)u4[2], (float)t4[2], -az);
    hn.w = fmaf((float)u4[3], (float)t4[3], -aw);
    o4[(NSTEP - 1) * S4 + idx] = hn;
    bf16x4 hb = {(bf16)hn.x, (bf16)hn.y, (bf16)hn.z, (bf16)hn.w};
    ((bf16x4*)hnb)[idx] = hb;
}

// ---------------------------------------------------------------------------
extern "C" void kernel_launch(void* const* d_in, const int* in_sizes, int n_in,
                              void* d_out, int out_size, void* d_ws, size_t ws_size,
                              hipStream_t stream) {
    const float* sample   = (const float*)d_in[0];
    const float* hiddens  = (const float*)d_in[1];
    const float* mem_para = (const float*)d_in[2];
    const float* Wu = (const float*)d_in[3];
    const float* bu = (const float*)d_in[4];
    const float* Wr = (const float*)d_in[5];
    const float* br = (const float*)d_in[6];
    const float* Wm = (const float*)d_in[7];
    const float* bm = (const float*)d_in[8];
    const float* Wh = (const float*)d_in[9];
    const float* bh = (const float*)d_in[10];
    const float* Wo = (const float*)d_in[11];
    const float* bo = (const float*)d_in[12];

    float* out        = (float*)d_out;
    float* out_output = out;                                  // [B,512]
    float* out_upd    = out + SLICE;                          // [16,B,512]
    float* out_mg     = out + SLICE + (size_t)NSTEP * SLICE;  // [B,512]

    const float* hidden = hiddens + (size_t)(NSTEP - 1) * SLICE;

    // workspace layout; 4MB-aligned chunks
    char* ws = (char*)d_ws;
    bf16* Sb    = (bf16*)(ws);                          // sample bf16
    bf16* Hb    = (bf16*)(ws + (((size_t) 4) << 20));   // hidden bf16
    bf16* Mb    = (bf16*)(ws + (((size_t) 8) << 20));   // mem_para bf16
    bf16* RHb   = (bf16*)(ws + (((size_t)12) << 20));   // reset_gate*hidden
    bf16* HNb   = (bf16*)(ws + (((size_t)16) << 20));   // hidden_now
    bf16* UGb   = (bf16*)(ws + (((size_t)20) << 20));   // update_gate
    bf16* HTb   = (bf16*)(ws + (((size_t)24) << 20));   // h_tilde
    bf16* Wall_t = (bf16*)(ws + (((size_t)28) << 20));  // [1536][1536] (4.5MB)
    bf16* Wh_t  = (bf16*)(ws + (((size_t)33) << 20));   // [512][1024]
    bf16* Wo_t  = (bf16*)(ws + (((size_t)35) << 20));   // [512][512]

    dim3 blk(256);
    const int n4 = SLICE / 4;

    // 1. fused prep: converts + all weight transposes
    prep_all<<<8704, blk, 0, stream>>>(sample, hidden, mem_para,
                                       Wu, Wr, Wm, Wh, Wo,
                                       Sb, Hb, Mb, Wall_t, Wh_t, Wo_t);
    // 2. fused U|R|M gates: N=1536, per-block K (U/R:1024, M:1536)
    gemm_urm<<<dim3(32, 12), blk, 0, stream>>>(
        Sb, Hb, Mb, Wall_t, bu, br, bm, UGb, RHb, out_mg);
    // 3. h_tilde = tanh([sample, rh] @ Wh + bh): N=512, K=1024
    gemm_mfma<2, 16><<<dim3(32, 8), blk, 0, stream>>>(
        Sb, RHb, Wh_t, 1024, bh, HTb);
    // 4. filter + shifted copy + hidden_now
    filter_combine<<<n4 / 256, blk, 0, stream>>>(hiddens, UGb, HTb, out_mg, out_upd, HNb);
    // 5. output = hidden_now @ Wo + bo: N=512, K=512
    gemm_mfma<3, 8><<<dim3(32, 8), blk, 0, stream>>>(
        HNb, nullptr, Wo_t, 512, bo, out_output);
}

// Round 6
// 130.325 us; speedup vs baseline: 1.1097x; 1.1097x over previous
//
#include <hip/hip_runtime.h>
#include <math.h>

typedef __bf16 bf16;
typedef __bf16 bf16x8 __attribute__((ext_vector_type(8)));
typedef __bf16 bf16x4 __attribute__((ext_vector_type(4)));
typedef float  f32x4  __attribute__((ext_vector_type(4)));

constexpr int BATCH = 4096;
constexpr int HID   = 512;
constexpr int NSTEP = 16;
constexpr int SLICE = BATCH * HID;   // elements per [B,H] plane

__device__ __forceinline__ float sigmoidf_(float x) {
    return 1.0f / (1.0f + __expf(-x));
}
__device__ __forceinline__ float tanh_fast(float x) {
    x = fminf(fmaxf(x, -15.0f), 15.0f);
    float e = __expf(2.0f * x);
    return (e - 1.0f) / (e + 1.0f);
}

__device__ __forceinline__ void gload_lds16(const void* g, void* l) {
    __builtin_amdgcn_global_load_lds((const __attribute__((address_space(1))) void*)g,
                                     (__attribute__((address_space(3))) void*)l,
                                     16, 0, 0);
}

// ---------------------------------------------------------------------------
// Fused prep: blocks [0,6144) convert sample/hidden/mem_para f32->bf16;
// blocks [6144,8704) transpose-convert the five weight matrices to B^T bf16.
__global__ __launch_bounds__(256)
void prep_all(const float* __restrict__ sample,
              const float* __restrict__ hidden,
              const float* __restrict__ mem_para,
              const float* __restrict__ Wu, const float* __restrict__ Wr,
              const float* __restrict__ Wm, const float* __restrict__ Wh,
              const float* __restrict__ Wo,
              bf16* __restrict__ Sb, bf16* __restrict__ Hb, bf16* __restrict__ Mb,
              bf16* __restrict__ Wall_t, bf16* __restrict__ Wh_t,
              bf16* __restrict__ Wo_t) {
    __shared__ float tile[32][33];
    const int bid = blockIdx.x;
    if (bid < 6144) {
        const int seg = bid >> 11;              // 0,1,2
        const int i = (bid & 2047) * 256 + threadIdx.x; // float4 index < SLICE/4
        const float* in = (seg == 0) ? sample : (seg == 1) ? hidden : mem_para;
        bf16* out = (seg == 0) ? Sb : (seg == 1) ? Hb : Mb;
        float4 v = ((const float4*)in)[i];
        bf16x4 o = {(bf16)v.x, (bf16)v.y, (bf16)v.z, (bf16)v.w};
        ((bf16x4*)out)[i] = o;
        return;
    }
    const int t = bid - 6144;                   // 0..2559: 32x32 transpose tiles
    const float* in; bf16* out; int stride, row_off, t2;
    if (t < 512)        { in = Wu; out = Wall_t; stride = 1536; row_off = 0;    t2 = t; }
    else if (t < 1024)  { in = Wr; out = Wall_t; stride = 1536; row_off = 512;  t2 = t - 512; }
    else if (t < 1792)  { in = Wm; out = Wall_t; stride = 1536; row_off = 1024; t2 = t - 1024; }
    else if (t < 2304)  { in = Wh; out = Wh_t;   stride = 1024; row_off = 0;    t2 = t - 1792; }
    else                { in = Wo; out = Wo_t;   stride = 512;  row_off = 0;    t2 = t - 2304; }
    const int r0 = (t2 >> 4) * 32, c0 = (t2 & 15) * 32;
    const int tr = threadIdx.x >> 5;   // 0..7
    const int tc = threadIdx.x & 31;   // 0..31
#pragma unroll
    for (int i = 0; i < 4; ++i)
        tile[tr + i * 8][tc] = in[(size_t)(r0 + tr + i * 8) * 512 + c0 + tc];
    __syncthreads();
#pragma unroll
    for (int i = 0; i < 4; ++i) {
        const int c = tr + i * 8;
        out[(size_t)(row_off + c0 + c) * stride + r0 + tc] = (bf16)tile[tc][c];
    }
}

// ---------------------------------------------------------------------------
// Fused U|R|M GEMM, tile BM=128 BN=64 BK=64; 256 thr = 4 waves (2x2),
// wave tile 64x32. Grid 32x24 = 768 blocks (3/CU). Per-block K: U/R
// column-blocks (bcol<1024) run 16 K-tiles; M blocks run 24. Wall_t rows
// 0..1023 are never read past k=1024 (no zero-pad needed).
// Epilogue: col<512: ug=sigmoid -> bf16 UGb; <1024: rh=sigmoid*hb -> bf16 RHb;
//           >=1024: mg=0.5*sigmoid -> f32 out_mg.
__global__ __launch_bounds__(256)
void gemm_urm(const bf16* __restrict__ Sb,
              const bf16* __restrict__ Hb,
              const bf16* __restrict__ Mb,
              const bf16* __restrict__ Wall_t,
              const float* __restrict__ bu,
              const float* __restrict__ br,
              const float* __restrict__ bm,
              bf16* __restrict__ UGb,
              bf16* __restrict__ RHb,
              float* __restrict__ out_mg) {
    __shared__ bf16 As[128 * 64];   // 16KB
    __shared__ bf16 Bs[64 * 64];    // 8KB

    const int tid  = threadIdx.x;
    const int wid  = tid >> 6;
    const int lane = tid & 63;
    const int wr = wid >> 1, wc = wid & 1;
    const int brow = blockIdx.x * 128;
    const int bcol = blockIdx.y * 64;

    const bf16* segs[3] = {Sb, Hb, Mb};
    const int nkt = (bcol >= 1024) ? 24 : 16;

    const int s_row  = tid >> 3;   // 0..31 (plus c*32)
    const int s_chnk = tid & 7;

    f32x4 acc[4][2] = {};

    for (int t = 0; t < nkt; ++t) {
        const int k0 = t * 64;
        const bf16* Aseg = segs[k0 >> 9];
        const int kloc = k0 & 511;

#pragma unroll
        for (int c = 0; c < 4; ++c) {
            const int row = c * 32 + s_row;
            const int sc  = s_chnk ^ (row & 7);
            gload_lds16(Aseg + (size_t)(brow + row) * 512 + kloc + sc * 8,
                        As + (size_t)(c * 256 + (wid << 6)) * 8);
        }
#pragma unroll
        for (int c = 0; c < 2; ++c) {
            const int row = c * 32 + s_row;
            const int sc  = s_chnk ^ (row & 7);
            gload_lds16(Wall_t + (size_t)(bcol + row) * 1536 + k0 + sc * 8,
                        Bs + (size_t)(c * 256 + (wid << 6)) * 8);
        }
        __syncthreads();

#pragma unroll
        for (int ks = 0; ks < 2; ++ks) {
            const int kb = ks * 64 + ((lane >> 4) << 4);
            bf16x8 bfrag[2];
#pragma unroll
            for (int ni = 0; ni < 2; ++ni) {
                const int n = wc * 32 + ni * 16 + (lane & 15);
                bfrag[ni] = *(const bf16x8*)((const char*)Bs +
                                             n * 128 + (kb ^ ((n & 7) << 4)));
            }
#pragma unroll
            for (int mi = 0; mi < 4; ++mi) {
                const int m = wr * 64 + mi * 16 + (lane & 15);
                const bf16x8 afrag = *(const bf16x8*)((const char*)As +
                                                      m * 128 + (kb ^ ((m & 7) << 4)));
#pragma unroll
                for (int ni = 0; ni < 2; ++ni)
                    acc[mi][ni] = __builtin_amdgcn_mfma_f32_16x16x32_bf16(
                        afrag, bfrag[ni], acc[mi][ni], 0, 0, 0);
            }
        }
        __syncthreads();
    }

    const int lr4 = (lane >> 4) * 4;
    const int lc  = lane & 15;
#pragma unroll
    for (int mi = 0; mi < 4; ++mi) {
#pragma unroll
        for (int ni = 0; ni < 2; ++ni) {
            const int col = bcol + wc * 32 + ni * 16 + lc;
            const f32x4 a = acc[mi][ni];
#pragma unroll
            for (int r = 0; r < 4; ++r) {
                const int row = brow + wr * 64 + mi * 16 + lr4 + r;
                const float x = a[r];
                if (col < 512) {
                    UGb[(size_t)row * 512 + col] = (bf16)sigmoidf_(x + bu[col]);
                } else if (col < 1024) {
                    const int c2 = col - 512;
                    const float v = sigmoidf_(x + br[c2]) *
                                    (float)Hb[(size_t)row * 512 + c2];
                    RHb[(size_t)row * 512 + c2] = (bf16)v;
                } else {
                    const int c3 = col - 1024;
                    out_mg[(size_t)row * 512 + c3] = 0.5f * sigmoidf_(x + bm[c3]);
                }
            }
        }
    }
}

// ---------------------------------------------------------------------------
// Skinny GEMM (N=512): tile BM=128 BN=64 BK=64; 4 waves 2x2, wave 64x32.
// ACT: 2 = tanh -> bf16 outA;  3 = identity(+bias) -> f32 outA
template <int ACT, int KTILES>
__global__ __launch_bounds__(256)
void gemm_mfma(const bf16* __restrict__ segA0,
               const bf16* __restrict__ segA1,
               const bf16* __restrict__ Wt, int ldK,
               const float* __restrict__ b0,
               void* __restrict__ outA) {
    __shared__ bf16 As[128 * 64];   // 16KB
    __shared__ bf16 Bs[64 * 64];    // 8KB

    const int tid  = threadIdx.x;
    const int wid  = tid >> 6;
    const int lane = tid & 63;
    const int wr = wid >> 1, wc = wid & 1;
    const int brow = blockIdx.x * 128;
    const int bcol = blockIdx.y * 64;

    const bf16* segs[2] = {segA0, segA1};

    const int s_row  = tid >> 3;
    const int s_chnk = tid & 7;

    f32x4 acc[4][2] = {};

    for (int t = 0; t < KTILES; ++t) {
        const int k0 = t * 64;
        const bf16* Aseg = segs[k0 >> 9];
        const int kloc = k0 & 511;

#pragma unroll
        for (int c = 0; c < 4; ++c) {
            const int row = c * 32 + s_row;
            const int sc  = s_chnk ^ (row & 7);
            gload_lds16(Aseg + (size_t)(brow + row) * 512 + kloc + sc * 8,
                        As + (size_t)(c * 256 + (wid << 6)) * 8);
        }
#pragma unroll
        for (int c = 0; c < 2; ++c) {
            const int row = c * 32 + s_row;
            const int sc  = s_chnk ^ (row & 7);
            gload_lds16(Wt + (size_t)(bcol + row) * ldK + k0 + sc * 8,
                        Bs + (size_t)(c * 256 + (wid << 6)) * 8);
        }
        __syncthreads();

#pragma unroll
        for (int ks = 0; ks < 2; ++ks) {
            const int kb = ks * 64 + ((lane >> 4) << 4);
            bf16x8 bfrag[2];
#pragma unroll
            for (int ni = 0; ni < 2; ++ni) {
                const int n = wc * 32 + ni * 16 + (lane & 15);
                bfrag[ni] = *(const bf16x8*)((const char*)Bs +
                                             n * 128 + (kb ^ ((n & 7) << 4)));
            }
#pragma unroll
            for (int mi = 0; mi < 4; ++mi) {
                const int m = wr * 64 + mi * 16 + (lane & 15);
                const bf16x8 afrag = *(const bf16x8*)((const char*)As +
                                                      m * 128 + (kb ^ ((m & 7) << 4)));
#pragma unroll
                for (int ni = 0; ni < 2; ++ni)
                    acc[mi][ni] = __builtin_amdgcn_mfma_f32_16x16x32_bf16(
                        afrag, bfrag[ni], acc[mi][ni], 0, 0, 0);
            }
        }
        __syncthreads();
    }

    const int lr4 = (lane >> 4) * 4;
    const int lc  = lane & 15;
#pragma unroll
    for (int mi = 0; mi < 4; ++mi) {
#pragma unroll
        for (int ni = 0; ni < 2; ++ni) {
            const int col = bcol + wc * 32 + ni * 16 + lc;
            const f32x4 a = acc[mi][ni];
#pragma unroll
            for (int r = 0; r < 4; ++r) {
                const int row = brow + wr * 64 + mi * 16 + lr4 + r;
                const float x = a[r];
                if constexpr (ACT == 2) {
                    ((bf16*)outA)[(size_t)row * 512 + col] = (bf16)tanh_fast(x + b0[col]);
                } else {
                    ((float*)outA)[(size_t)row * 512 + col] = x + b0[col];
                }
            }
        }
    }
}

// ---------------------------------------------------------------------------
// Fused memory filter + shifted copy + hidden_now (f32 out + bf16 copy)
__global__ __launch_bounds__(256)
void filter_combine(const float* __restrict__ hiddens,
                    const bf16* __restrict__ ugb,
                    const bf16* __restrict__ htb,
                    const float* __restrict__ mg,
                    float* __restrict__ out_upd,
                    bf16* __restrict__ hnb) {
    const int idx = blockIdx.x * blockDim.x + threadIdx.x;   // float4 index
    const int S4 = SLICE / 4;
    const float4* h4 = (const float4*)hiddens;
    float4* o4 = (float4*)out_upd;

    const float4 d = ((const float4*)mg)[idx];
    float cx = 1.f, cy = 1.f, cz = 1.f, cw = 1.f;
    float ax = 0.f, ay = 0.f, az = 0.f, aw = 0.f;

#pragma unroll
    for (int i = 0; i < NSTEP; ++i) {
        const int j = NSTEP - 1 - i;
        const float4 v = h4[j * S4 + idx];
        const float fi = (float)i;
        const float inv = 1.0f / (float)(i + 1);
        cx *= (fi - d.x) * inv;
        cy *= (fi - d.y) * inv;
        cz *= (fi - d.z) * inv;
        cw *= (fi - d.w) * inv;
        ax = fmaf(v.x, cx, ax);
        ay = fmaf(v.y, cy, ay);
        az = fmaf(v.z, cz, az);
        aw = fmaf(v.w, cw, aw);
        if (j >= 1) o4[(j - 1) * S4 + idx] = v;
    }

    const bf16x4 u4 = ((const bf16x4*)ugb)[idx];
    const bf16x4 t4 = ((const bf16x4*)htb)[idx];
    float4 hn;
    hn.x = fmaf((float)u4[0], (float)t4[0], -ax);
    hn.y = fmaf((float)u4[1], (float)t4[1], -ay);
    hn.z = fmaf((float)u4[2], (float)t4[2], -az);
    hn.w = fmaf((float)u4[3], (float)t4[3], -aw);
    o4[(NSTEP - 1) * S4 + idx] = hn;
    bf16x4 hb = {(bf16)hn.x, (bf16)hn.y, (bf16)hn.z, (bf16)hn.w};
    ((bf16x4*)hnb)[idx] = hb;
}

// ---------------------------------------------------------------------------
extern "C" void kernel_launch(void* const* d_in, const int* in_sizes, int n_in,
                              void* d_out, int out_size, void* d_ws, size_t ws_size,
                              hipStream_t stream) {
    const float* sample   = (const float*)d_in[0];
    const float* hiddens  = (const float*)d_in[1];
    const float* mem_para = (const float*)d_in[2];
    const float* Wu = (const float*)d_in[3];
    const float* bu = (const float*)d_in[4];
    const float* Wr = (const float*)d_in[5];
    const float* br = (const float*)d_in[6];
    const float* Wm = (const float*)d_in[7];
    const float* bm = (const float*)d_in[8];
    const float* Wh = (const float*)d_in[9];
    const float* bh = (const float*)d_in[10];
    const float* Wo = (const float*)d_in[11];
    const float* bo = (const float*)d_in[12];

    float* out        = (float*)d_out;
    float* out_output = out;                                  // [B,512]
    float* out_upd    = out + SLICE;                          // [16,B,512]
    float* out_mg     = out + SLICE + (size_t)NSTEP * SLICE;  // [B,512]

    const float* hidden = hiddens + (size_t)(NSTEP - 1) * SLICE;

    // workspace layout; 4MB-aligned chunks
    char* ws = (char*)d_ws;
    bf16* Sb    = (bf16*)(ws);                          // sample bf16
    bf16* Hb    = (bf16*)(ws + (((size_t) 4) << 20));   // hidden bf16
    bf16* Mb    = (bf16*)(ws + (((size_t) 8) << 20));   // mem_para bf16
    bf16* RHb   = (bf16*)(ws + (((size_t)12) << 20));   // reset_gate*hidden
    bf16* HNb   = (bf16*)(ws + (((size_t)16) << 20));   // hidden_now
    bf16* UGb   = (bf16*)(ws + (((size_t)20) << 20));   // update_gate
    bf16* HTb   = (bf16*)(ws + (((size_t)24) << 20));   // h_tilde
    bf16* Wall_t = (bf16*)(ws + (((size_t)28) << 20));  // [1536][1536] (4.5MB)
    bf16* Wh_t  = (bf16*)(ws + (((size_t)33) << 20));   // [512][1024]
    bf16* Wo_t  = (bf16*)(ws + (((size_t)35) << 20));   // [512][512]

    dim3 blk(256);
    const int n4 = SLICE / 4;

    // 1. fused prep: converts + all weight transposes
    prep_all<<<8704, blk, 0, stream>>>(sample, hidden, mem_para,
                                       Wu, Wr, Wm, Wh, Wo,
                                       Sb, Hb, Mb, Wall_t, Wh_t, Wo_t);
    // 2. fused U|R|M gates: N=1536, BN=64, per-block K (U/R:16kt, M:24kt)
    gemm_urm<<<dim3(32, 24), blk, 0, stream>>>(
        Sb, Hb, Mb, Wall_t, bu, br, bm, UGb, RHb, out_mg);
    // 3. h_tilde = tanh([sample, rh] @ Wh + bh): N=512, K=1024
    gemm_mfma<2, 16><<<dim3(32, 8), blk, 0, stream>>>(
        Sb, RHb, Wh_t, 1024, bh, HTb);
    // 4. filter + shifted copy + hidden_now
    filter_combine<<<n4 / 256, blk, 0, stream>>>(hiddens, UGb, HTb, out_mg, out_upd, HNb);
    // 5. output = hidden_now @ Wo + bo: N=512, K=512
    gemm_mfma<3, 8><<<dim3(32, 8), blk, 0, stream>>>(
        HNb, nullptr, Wo_t, 512, bo, out_output);
}